// Round 20
// baseline (223.342 us; speedup 1.0000x reference)
//
#include <hip/hip_runtime.h>

#define Lq 512
#define Bn 1024
#define Tq 48

typedef float f32x4 __attribute__((ext_vector_type(4)));
typedef short s16x8 __attribute__((ext_vector_type(8)));
typedef unsigned u32x4 __attribute__((ext_vector_type(4)));

#define MFMA(a, b, c) __builtin_amdgcn_mfma_f32_16x16x32_bf16((a), (b), (c), 0, 0, 0)
#define SB __builtin_amdgcn_sched_barrier(0)

__device__ __forceinline__ unsigned cvtpk(float lo, float hi) {
    unsigned r;
    asm("v_cvt_pk_bf16_f32 %0, %1, %2" : "=v"(r) : "v"(lo), "v"(hi));
    return r;
}
__device__ __forceinline__ short f2b(float x) {       // fp32 -> bf16 bits, RNE
    unsigned u = __float_as_uint(x);
    return (short)((u + 0x7fffu + ((u >> 16) & 1u)) >> 16);
}

// ---- per-stream macros (S = A or B) ----------------------------------------
#define PACKBX(S) do {                                                        \
    unsigned d0_ = cvtpk(pn##S##0[0], pn##S##0[1]);                           \
    unsigned d1_ = cvtpk(pn##S##0[2], pn##S##0[3]);                           \
    unsigned d2_ = cvtpk(pn##S##1[0], pn##S##1[1]);                           \
    unsigned d3_ = cvtpk(pn##S##1[2], pn##S##1[3]);                           \
    unsigned d4_ = cvtpk(pn##S##2[0], pn##S##2[1]);                           \
    unsigned d5_ = cvtpk(pn##S##2[2], pn##S##2[3]);                           \
    u32x4 b0_ = {d0_, d1_, d2_, d3_};                                         \
    u32x4 b1_ = {d4_, d5_, 0u, 0u};                                           \
    Bk##S##0 = __builtin_bit_cast(s16x8, b0_);                                \
    Bk##S##1 = __builtin_bit_cast(s16x8, b1_);                                \
} while (0)

// one step for stream S; EA/EB/EC pre-exponentiated [R19-proven]
#define STEPX(S, EA, EB, EC, MV, RS) do {                                     \
    f32x4 C0_ = MFMA(aw00, Bk##S##0, Zf); C0_ = MFMA(aw01, Bk##S##1, C0_);    \
    f32x4 C1_ = MFMA(aw10, Bk##S##0, Zf); C1_ = MFMA(aw11, Bk##S##1, C1_);    \
    f32x4 C2_ = MFMA(aw20, Bk##S##0, Zf); C2_ = MFMA(aw21, Bk##S##1, C2_);    \
    pn##S##0[0] = (MV) ? C0_[0] * (EA)[0] : pn##S##0[0];                      \
    pn##S##0[1] = (MV) ? C0_[1] * (EA)[1] : pn##S##0[1];                      \
    pn##S##0[2] = (MV) ? C0_[2] * (EA)[2] : pn##S##0[2];                      \
    pn##S##0[3] = (MV) ? C0_[3] * (EA)[3] : pn##S##0[3];                      \
    pn##S##1[0] = (MV) ? C1_[0] * (EB)[0] : pn##S##1[0];                      \
    pn##S##1[1] = (MV) ? C1_[1] * (EB)[1] : pn##S##1[1];                      \
    pn##S##1[2] = (MV) ? C1_[2] * (EB)[2] : pn##S##1[2];                      \
    pn##S##1[3] = (MV) ? C1_[3] * (EB)[3] : pn##S##1[3];                      \
    pn##S##2[0] = (MV) ? C2_[0] * (EC)[0] : pn##S##2[0];                      \
    pn##S##2[1] = (MV) ? C2_[1] * (EC)[1] : pn##S##2[1];                      \
    pn##S##2[2] = (MV) ? C2_[2] * (EC)[2] : pn##S##2[2];                      \
    pn##S##2[3] = (MV) ? C2_[3] * (EC)[3] : pn##S##2[3];                      \
    if (RS) {                                                                 \
        pn##S##0[0]*=scl##S; pn##S##0[1]*=scl##S;                             \
        pn##S##0[2]*=scl##S; pn##S##0[3]*=scl##S;                             \
        pn##S##1[0]*=scl##S; pn##S##1[1]*=scl##S;                             \
        pn##S##1[2]*=scl##S; pn##S##1[3]*=scl##S;                             \
        pn##S##2[0]*=scl##S; pn##S##2[1]*=scl##S;                             \
        pn##S##2[2]*=scl##S; pn##S##2[3]*=scl##S;                             \
        c2##S += k##S;                                                        \
    }                                                                         \
    PACKBX(S);                                                                \
} while (0)

// exponent read one step before application [R19-proven]
#define KREADX(S) do {                                                        \
    float rep_ = __shfl(pn##S##0[0], cidx, 64);                               \
    k##S = ((__float_as_int(rep_) >> 23) & 0xff) - 126;                       \
    scl##S = __int_as_float((127 - k##S) << 23);                              \
} while (0)

// asm-pinned slot refill [R16-proven]
#define LOAD_SLOTX(S, D, T) do {                                              \
    int t_ = (T); vf##S##_##D = (t_ < Lq); int tc_ = vf##S##_##D ? t_ : (Lq - 1); \
    const float* ep_ = em + ((size_t)tc_ * Bn + bidx##S) * Tq + 4 * qidx;     \
    const int*   mp_ = mask + tc_ * Bn + bidx##S;                             \
    asm volatile("global_load_dwordx4 %0, %1, off" : "=v"(ea##S##_##D) : "v"(ep_));      \
    asm volatile("global_load_dwordx4 %0, %1, off" : "=v"(eb##S##_##D) : "v"(ep_ + 16)); \
    asm volatile("global_load_dwordx4 %0, %1, off" : "=v"(ec##S##_##D) : "v"(ep_ + 32)); \
    asm volatile("global_load_dword %0, %1, off"   : "=v"(mv##S##_##D) : "v"(mp_));      \
} while (0)

// in-place exponentiation of a completed slot (pipeline stage) [R19-proven]
#define EXP_SLOTX(S, D) do {                                                  \
    ea##S##_##D[0]=__expf(ea##S##_##D[0]); ea##S##_##D[1]=__expf(ea##S##_##D[1]); \
    ea##S##_##D[2]=__expf(ea##S##_##D[2]); ea##S##_##D[3]=__expf(ea##S##_##D[3]); \
    eb##S##_##D[0]=__expf(eb##S##_##D[0]); eb##S##_##D[1]=__expf(eb##S##_##D[1]); \
    eb##S##_##D[2]=__expf(eb##S##_##D[2]); eb##S##_##D[3]=__expf(eb##S##_##D[3]); \
    ec##S##_##D[0]=__expf(ec##S##_##D[0]); ec##S##_##D[1]=__expf(ec##S##_##D[1]); \
    ec##S##_##D[2]=__expf(ec##S##_##D[2]); ec##S##_##D[3]=__expf(ec##S##_##D[3]); \
} while (0)

// wait until the two OLDEST slots (both streams) are complete: 32 in flight
// max, 16 newest allowed to remain (= 2 supersteps x 8 loads).
#define WAIT16 do { asm volatile("s_waitcnt vmcnt(16)"); SB; } while (0)

// ---------------- Fused kernel ----------------
// blocks 0..31: dual-stream MFMA forward (2 x 16 batch columns per wave);
//               stream B's chain fills stream A's dependency stalls.
// blocks 32..543: numerator (gold-path score), grid-stride.
__global__ __launch_bounds__(64, 1) void crf_fused(
    const float* __restrict__ em, const int* __restrict__ tags,
    const int* __restrict__ mask, const float* __restrict__ startT,
    const float* __restrict__ endT, const float* __restrict__ trans,
    float* __restrict__ out)
{
    const int j = threadIdx.x;
    __shared__ float shf[Tq * Tq];

    if (blockIdx.x < 32) {
        // ---------------- forward path ----------------
        const int cidx = j & 15;
        const int qidx = j >> 4;
        const int bidxA = blockIdx.x * 32 + cidx;
        const int bidxB = bidxA + 16;

        // stage trans, build shared W^T A-fragments (kappa permutation)
        for (int i = j; i < Tq * Tq; i += 64) shf[i] = trans[i];
        __syncthreads();
        s16x8 aw00, aw01, aw10, aw11, aw20, aw21;
#pragma unroll
        for (int i = 0; i < 8; ++i) {
            int l0 = (i < 4) ? (4 * qidx + i) : (12 + 4 * qidx + i);
            aw00[i] = f2b(__expf(shf[l0 * Tq + cidx]));
            aw10[i] = f2b(__expf(shf[l0 * Tq + 16 + cidx]));
            aw20[i] = f2b(__expf(shf[l0 * Tq + 32 + cidx]));
            if (i < 4) {
                int l1 = 32 + 4 * qidx + i;
                aw01[i] = f2b(__expf(shf[l1 * Tq + cidx]));
                aw11[i] = f2b(__expf(shf[l1 * Tq + 16 + cidx]));
                aw21[i] = f2b(__expf(shf[l1 * Tq + 32 + cidx]));
            } else {
                aw01[i] = 0; aw11[i] = 0; aw21[i] = 0;
            }
        }

        // P_0 for both streams
        f32x4 pnA0, pnA1, pnA2, pnB0, pnB1, pnB2;
#pragma unroll
        for (int s = 0; s < 2; ++s) {
            const float* e0p = em + (size_t)(s ? bidxB : bidxA) * Tq;
            f32x4 ea = *(const f32x4*)(e0p + 4 * qidx);
            f32x4 eb = *(const f32x4*)(e0p + 16 + 4 * qidx);
            f32x4 ec = *(const f32x4*)(e0p + 32 + 4 * qidx);
            f32x4 p0, p1, p2;
#pragma unroll
            for (int i = 0; i < 4; ++i) {
                p0[i] = __expf(startT[ 0 + 4 * qidx + i] + ea[i]);
                p1[i] = __expf(startT[16 + 4 * qidx + i] + eb[i]);
                p2[i] = __expf(startT[32 + 4 * qidx + i] + ec[i]);
            }
            if (s) { pnB0 = p0; pnB1 = p1; pnB2 = p2; }
            else   { pnA0 = p0; pnA1 = p1; pnA2 = p2; }
        }

        const f32x4 Zf = {0.f, 0.f, 0.f, 0.f};
        s16x8 BkA0, BkA1, BkB0, BkB1;
        int c2A = 0, c2B = 0;
        int kA = 0, kB = 0;
        float sclA = 1.0f, sclB = 1.0f;
        PACKBX(A); PACKBX(B);

        // 4 slots x 2 streams, asm-pinned registers
        f32x4 eaA_0, ebA_0, ecA_0, eaA_1, ebA_1, ecA_1;
        f32x4 eaA_2, ebA_2, ecA_2, eaA_3, ebA_3, ecA_3;
        f32x4 eaB_0, ebB_0, ecB_0, eaB_1, ebB_1, ecB_1;
        f32x4 eaB_2, ebB_2, ecB_2, eaB_3, ebB_3, ecB_3;
        int mvA_0, mvA_1, mvA_2, mvA_3, mvB_0, mvB_1, mvB_2, mvB_3;
        int vfA_0, vfA_1, vfA_2, vfA_3, vfB_0, vfB_1, vfB_2, vfB_3;

        asm volatile("s_waitcnt vmcnt(0)");
        LOAD_SLOTX(A, 0, 1); LOAD_SLOTX(B, 0, 1);
        LOAD_SLOTX(A, 1, 2); LOAD_SLOTX(B, 1, 2);
        LOAD_SLOTX(A, 2, 3); LOAD_SLOTX(B, 2, 3);
        LOAD_SLOTX(A, 3, 4); LOAD_SLOTX(B, 3, 4);
        WAIT16;                       // slots 0,1 (both streams) complete
        EXP_SLOTX(A, 0); EXP_SLOTX(B, 0);

        // 128 chunks x 4 supersteps; each superstep advances BOTH streams.
        // exp stage one superstep ahead; k read at pos2, applied pos3.
        for (int ch = 0; ch < 128; ++ch) {
            const int tb = 1 + 4 * ch;
            WAIT16;
            EXP_SLOTX(A, 1); EXP_SLOTX(B, 1);
            STEPX(A, eaA_0, ebA_0, ecA_0, (mvA_0 & vfA_0), 0);
            STEPX(B, eaB_0, ebB_0, ecB_0, (mvB_0 & vfB_0), 0);
            LOAD_SLOTX(A, 0, tb + 4); LOAD_SLOTX(B, 0, tb + 4);

            WAIT16;
            EXP_SLOTX(A, 2); EXP_SLOTX(B, 2);
            STEPX(A, eaA_1, ebA_1, ecA_1, (mvA_1 & vfA_1), 0);
            STEPX(B, eaB_1, ebB_1, ecB_1, (mvB_1 & vfB_1), 0);
            LOAD_SLOTX(A, 1, tb + 5); LOAD_SLOTX(B, 1, tb + 5);

            WAIT16;
            EXP_SLOTX(A, 3); EXP_SLOTX(B, 3);
            STEPX(A, eaA_2, ebA_2, ecA_2, (mvA_2 & vfA_2), 0); KREADX(A);
            STEPX(B, eaB_2, ebB_2, ecB_2, (mvB_2 & vfB_2), 0); KREADX(B);
            LOAD_SLOTX(A, 2, tb + 6); LOAD_SLOTX(B, 2, tb + 6);

            WAIT16;
            EXP_SLOTX(A, 0); EXP_SLOTX(B, 0);
            STEPX(A, eaA_3, ebA_3, ecA_3, (mvA_3 & vfA_3), 1);
            STEPX(B, eaB_3, ebB_3, ecB_3, (mvB_3 & vfB_3), 1);
            LOAD_SLOTX(A, 3, tb + 7); LOAD_SLOTX(B, 3, tb + 7);
        }

        // epilogue per stream: z = sum_s P[s]*exp(end[s])
        float ezq0[4], ezq1[4], ezq2[4];
#pragma unroll
        for (int i = 0; i < 4; ++i) {
            ezq0[i] = __expf(endT[ 0 + 4 * qidx + i]);
            ezq1[i] = __expf(endT[16 + 4 * qidx + i]);
            ezq2[i] = __expf(endT[32 + 4 * qidx + i]);
        }
        float zA = 0.f, zB = 0.f;
#pragma unroll
        for (int i = 0; i < 4; ++i) {
            zA += pnA0[i] * ezq0[i] + pnA1[i] * ezq1[i] + pnA2[i] * ezq2[i];
            zB += pnB0[i] * ezq0[i] + pnB1[i] * ezq1[i] + pnB2[i] * ezq2[i];
        }
        zA += __shfl_xor(zA, 16, 64); zA += __shfl_xor(zA, 32, 64);
        zB += __shfl_xor(zB, 16, 64); zB += __shfl_xor(zB, 32, 64);
        float nl = -(__logf(zA) + (float)c2A * 0.6931471805599453f)
                 - (__logf(zB) + (float)c2B * 0.6931471805599453f);
        nl += __shfl_xor(nl, 1, 64);
        nl += __shfl_xor(nl, 2, 64);
        nl += __shfl_xor(nl, 4, 64);
        nl += __shfl_xor(nl, 8, 64);
        if (j == 0) atomicAdd(out, nl);
        asm volatile("s_waitcnt vmcnt(0)");   // drain in-flight asm loads
    } else {
        // ---------------- numerator path ----------------
        const int bid = blockIdx.x - 32;          // 0..511
        float c = 0.0f;
        for (int id = bid * 64 + j; id < Lq * Bn; id += 512 * 64) {
            int t  = id >> 10;
            int bb = id & (Bn - 1);
            int tag = tags[id];
            int m_t = mask[id];
            if (t == 0) c += startT[tag];
            bool is_last;
            if (t < Lq - 1) {
                if (m_t) c += em[(size_t)id * Tq + tag];
                int tag1 = tags[id + Bn];
                int m1   = mask[id + Bn];
                if (m1) c += trans[tag * Tq + tag1];
                is_last = (m_t != 0) && (m1 == 0);
            } else {
                is_last = (m_t != 0);
            }
            if (is_last) {
                c += endT[tag];
                int mL = mask[(Lq - 1) * Bn + bb];
                if (mL) c += em[((size_t)(Lq - 1) * Bn + bb) * Tq + tag];
            }
        }
#pragma unroll
        for (int off = 32; off >= 1; off >>= 1)
            c += __shfl_xor(c, off, 64);
        if (j == 0) atomicAdd(out, c);
    }
}

extern "C" void kernel_launch(void* const* d_in, const int* in_sizes, int n_in,
                              void* d_out, int out_size, void* d_ws, size_t ws_size,
                              hipStream_t stream) {
    const float* em     = (const float*)d_in[0];
    const int*   tags   = (const int*)d_in[1];
    const int*   mask   = (const int*)d_in[2];
    const float* startT = (const float*)d_in[3];
    const float* endT   = (const float*)d_in[4];
    const float* trans  = (const float*)d_in[5];
    float* out = (float*)d_out;

    hipMemsetAsync(out, 0, sizeof(float), stream);
    crf_fused<<<544, 64, 0, stream>>>(em, tags, mask, startT, endT, trans, out);
}

// Round 21
// 139.941 us; speedup vs baseline: 1.5960x; 1.5960x over previous
//
#include <hip/hip_runtime.h>

#define Lq 512
#define Bn 1024
#define Tq 48

typedef float f32x4 __attribute__((ext_vector_type(4)));
typedef short s16x8 __attribute__((ext_vector_type(8)));
typedef unsigned u32x4 __attribute__((ext_vector_type(4)));

#define MFMA(a, b, c) __builtin_amdgcn_mfma_f32_16x16x32_bf16((a), (b), (c), 0, 0, 0)
#define SB __builtin_amdgcn_sched_barrier(0)

__device__ __forceinline__ unsigned cvtpk(float lo, float hi) {
    unsigned r;
    asm("v_cvt_pk_bf16_f32 %0, %1, %2" : "=v"(r) : "v"(lo), "v"(hi));
    return r;
}
__device__ __forceinline__ short f2b(float x) {       // fp32 -> bf16 bits, RNE
    unsigned u = __float_as_uint(x);
    return (short)((u + 0x7fffu + ((u >> 16) & 1u)) >> 16);
}

// rebuild B fragments from this lane's own pn [R11-proven]
#define PACKB do {                                                            \
    unsigned d0_ = cvtpk(pn0[0], pn0[1]), d1_ = cvtpk(pn0[2], pn0[3]);        \
    unsigned d2_ = cvtpk(pn1[0], pn1[1]), d3_ = cvtpk(pn1[2], pn1[3]);        \
    unsigned d4_ = cvtpk(pn2[0], pn2[1]), d5_ = cvtpk(pn2[2], pn2[3]);        \
    u32x4 b0_ = {d0_, d1_, d2_, d3_};                                         \
    u32x4 b1_ = {d4_, d5_, 0u, 0u};                                           \
    Bk0 = __builtin_bit_cast(s16x8, b0_);                                     \
    Bk1 = __builtin_bit_cast(s16x8, b1_);                                     \
} while (0)

// exponent read (2 steps before application now; exact power-of-2)
#define KREAD do {                                                            \
    float rep_ = __shfl(pn0[0], cidx, 64);                                    \
    k_ = ((__float_as_int(rep_) >> 23) & 0xff) - 126;                         \
    scl_ = __int_as_float((127 - k_) << 23);                                  \
} while (0)

// asm-pinned slot refill (RAW e + mask) [R16-proven]
#define LOAD_SLOT(D, T) do {                                                  \
    int t_ = (T); vf_##D = (t_ < Lq); int tc_ = vf_##D ? t_ : (Lq - 1);       \
    const float* ep_ = em + ((size_t)tc_ * Bn + bidx) * Tq + 4 * qidx;        \
    const int*   mp_ = mask + tc_ * Bn + bidx;                                \
    asm volatile("global_load_dwordx4 %0, %1, off" : "=v"(ea_##D) : "v"(ep_));      \
    asm volatile("global_load_dwordx4 %0, %1, off" : "=v"(eb_##D) : "v"(ep_ + 16)); \
    asm volatile("global_load_dwordx4 %0, %1, off" : "=v"(ec_##D) : "v"(ep_ + 32)); \
    asm volatile("global_load_dword %0, %1, off"   : "=v"(mv_##D) : "v"(mp_));      \
} while (0)

// in-place exponentiation of a completed slot [R19-proven]
#define EXP_SLOT(D) do {                                                      \
    ea_##D[0]=__expf(ea_##D[0]); ea_##D[1]=__expf(ea_##D[1]);                 \
    ea_##D[2]=__expf(ea_##D[2]); ea_##D[3]=__expf(ea_##D[3]);                 \
    eb_##D[0]=__expf(eb_##D[0]); eb_##D[1]=__expf(eb_##D[1]);                 \
    eb_##D[2]=__expf(eb_##D[2]); eb_##D[3]=__expf(eb_##D[3]);                 \
    ec_##D[0]=__expf(ec_##D[0]); ec_##D[1]=__expf(ec_##D[1]);                 \
    ec_##D[2]=__expf(ec_##D[2]); ec_##D[3]=__expf(ec_##D[3]);                 \
} while (0)

// R21 step: filler work placed BETWEEN MFMA issue and MFMA consume.
// In-order issue => the wait+exp (+kread) run inside the MFMA latency
// shadow; SB fences pin the regions so the compiler cannot re-sink the
// dependent muls above the filler. Slot D is consumed (exp'd values from
// prior step's EXP), then refilled at the END for t+4.
#define STEPP(D, DN, T4, KR, RS) do {                                         \
    f32x4 C0_ = MFMA(aw00, Bk0, Zf); C0_ = MFMA(aw01, Bk1, C0_);              \
    f32x4 C1_ = MFMA(aw10, Bk0, Zf); C1_ = MFMA(aw11, Bk1, C1_);              \
    f32x4 C2_ = MFMA(aw20, Bk0, Zf); C2_ = MFMA(aw21, Bk1, C2_);              \
    asm volatile("s_waitcnt vmcnt(8)"); SB;   /* retire slot DN's 4 loads */  \
    EXP_SLOT(DN);                             /* fills MFMA latency shadow */ \
    if (KR) { KREAD; }                                                        \
    SB;                                                                       \
    int mvv_ = (mv_##D & vf_##D);                                             \
    pn0[0] = mvv_ ? C0_[0] * ea_##D[0] : pn0[0];                              \
    pn0[1] = mvv_ ? C0_[1] * ea_##D[1] : pn0[1];                              \
    pn0[2] = mvv_ ? C0_[2] * ea_##D[2] : pn0[2];                              \
    pn0[3] = mvv_ ? C0_[3] * ea_##D[3] : pn0[3];                              \
    pn1[0] = mvv_ ? C1_[0] * eb_##D[0] : pn1[0];                              \
    pn1[1] = mvv_ ? C1_[1] * eb_##D[1] : pn1[1];                              \
    pn1[2] = mvv_ ? C1_[2] * eb_##D[2] : pn1[2];                              \
    pn1[3] = mvv_ ? C1_[3] * eb_##D[3] : pn1[3];                              \
    pn2[0] = mvv_ ? C2_[0] * ec_##D[0] : pn2[0];                              \
    pn2[1] = mvv_ ? C2_[1] * ec_##D[1] : pn2[1];                              \
    pn2[2] = mvv_ ? C2_[2] * ec_##D[2] : pn2[2];                              \
    pn2[3] = mvv_ ? C2_[3] * ec_##D[3] : pn2[3];                              \
    if (RS) {                                                                 \
        pn0[0]*=scl_; pn0[1]*=scl_; pn0[2]*=scl_; pn0[3]*=scl_;               \
        pn1[0]*=scl_; pn1[1]*=scl_; pn1[2]*=scl_; pn1[3]*=scl_;               \
        pn2[0]*=scl_; pn2[1]*=scl_; pn2[2]*=scl_; pn2[3]*=scl_;               \
        c2 += k_;                                                             \
    }                                                                         \
    PACKB;                                                                    \
    LOAD_SLOT(D, T4);               /* refill AFTER consume (no overwrite) */ \
} while (0)

// ---------------- Fused kernel ----------------
// blocks 0..63: MFMA forward algorithm (16 batch columns per wave).
// blocks 64..575: numerator (gold-path score), grid-stride.
__global__ __launch_bounds__(64, 1) void crf_fused(
    const float* __restrict__ em, const int* __restrict__ tags,
    const int* __restrict__ mask, const float* __restrict__ startT,
    const float* __restrict__ endT, const float* __restrict__ trans,
    float* __restrict__ out)
{
    const int j = threadIdx.x;
    __shared__ float shf[Tq * Tq];

    if (blockIdx.x < 64) {
        // ---------------- forward path ----------------
        const int cidx = j & 15;          // batch column within wave
        const int qidx = j >> 4;          // k-slot group
        const int bidx = blockIdx.x * 16 + cidx;

        // stage trans, build W^T A-fragments (kappa permutation) [R11-proven]
        for (int i = j; i < Tq * Tq; i += 64) shf[i] = trans[i];
        __syncthreads();
        s16x8 aw00, aw01, aw10, aw11, aw20, aw21;
#pragma unroll
        for (int i = 0; i < 8; ++i) {
            int l0 = (i < 4) ? (4 * qidx + i) : (12 + 4 * qidx + i);
            aw00[i] = f2b(__expf(shf[l0 * Tq + cidx]));
            aw10[i] = f2b(__expf(shf[l0 * Tq + 16 + cidx]));
            aw20[i] = f2b(__expf(shf[l0 * Tq + 32 + cidx]));
            if (i < 4) {
                int l1 = 32 + 4 * qidx + i;
                aw01[i] = f2b(__expf(shf[l1 * Tq + cidx]));
                aw11[i] = f2b(__expf(shf[l1 * Tq + 16 + cidx]));
                aw21[i] = f2b(__expf(shf[l1 * Tq + 32 + cidx]));
            } else {
                aw01[i] = 0; aw11[i] = 0; aw21[i] = 0;
            }
        }

        // P_0 (C layout): pn_n[i] = exp(start[s]+em0[s]), s = 16n+4q+i
        f32x4 pn0, pn1, pn2;
        {
            const float* e0p = em + (size_t)bidx * Tq;
            f32x4 ea = *(const f32x4*)(e0p + 4 * qidx);
            f32x4 eb = *(const f32x4*)(e0p + 16 + 4 * qidx);
            f32x4 ec = *(const f32x4*)(e0p + 32 + 4 * qidx);
#pragma unroll
            for (int i = 0; i < 4; ++i) {
                pn0[i] = __expf(startT[ 0 + 4 * qidx + i] + ea[i]);
                pn1[i] = __expf(startT[16 + 4 * qidx + i] + eb[i]);
                pn2[i] = __expf(startT[32 + 4 * qidx + i] + ec[i]);
            }
        }

        const f32x4 Zf = {0.f, 0.f, 0.f, 0.f};
        s16x8 Bk0, Bk1;
        int c2 = 0;
        int k_ = 0; float scl_ = 1.0f;
        PACKB;

        // 4 prefetch slots in asm-pinned registers (raw -> exp'd in place)
        f32x4 ea_0, eb_0, ec_0, ea_1, eb_1, ec_1;
        f32x4 ea_2, eb_2, ec_2, ea_3, eb_3, ec_3;
        int mv_0, mv_1, mv_2, mv_3;
        int vf_0, vf_1, vf_2, vf_3;

        // prologue: zero vmcnt baseline, fill 4 slots, exp slot 0
        asm volatile("s_waitcnt vmcnt(0)");
        LOAD_SLOT(0, 1); LOAD_SLOT(1, 2); LOAD_SLOT(2, 3); LOAD_SLOT(3, 4);
        asm volatile("s_waitcnt vmcnt(12)"); SB;   // slot 0 complete
        EXP_SLOT(0);

        // 128 chunks x 4 steps; KREAD at pos 2 (filler), applied at pos 3
        for (int ch = 0; ch < 128; ++ch) {
            const int tb = 1 + 4 * ch;
            STEPP(0, 1, tb + 4, 0, 0);
            STEPP(1, 2, tb + 5, 0, 0);
            STEPP(2, 3, tb + 6, 1, 0);
            STEPP(3, 0, tb + 7, 0, 1);
        }

        // z_c = sum_s P[s][c]*exp(end[s]); states at this lane: 16n+4q+i
        float zacc = 0.f;
#pragma unroll
        for (int i = 0; i < 4; ++i) {
            zacc += pn0[i] * __expf(endT[ 0 + 4 * qidx + i]);
            zacc += pn1[i] * __expf(endT[16 + 4 * qidx + i]);
            zacc += pn2[i] * __expf(endT[32 + 4 * qidx + i]);
        }
        zacc += __shfl_xor(zacc, 16, 64);
        zacc += __shfl_xor(zacc, 32, 64);
        float nl = -(__logf(zacc) + (float)c2 * 0.6931471805599453f);
        nl += __shfl_xor(nl, 1, 64);
        nl += __shfl_xor(nl, 2, 64);
        nl += __shfl_xor(nl, 4, 64);
        nl += __shfl_xor(nl, 8, 64);
        if (j == 0) atomicAdd(out, nl);
        asm volatile("s_waitcnt vmcnt(0)");   // drain in-flight asm loads
    } else {
        // ---------------- numerator path ----------------
        const int bid = blockIdx.x - 64;          // 0..511
        float c = 0.0f;
        for (int id = bid * 64 + j; id < Lq * Bn; id += 512 * 64) {
            int t  = id >> 10;
            int bb = id & (Bn - 1);
            int tag = tags[id];
            int m_t = mask[id];
            if (t == 0) c += startT[tag];
            bool is_last;
            if (t < Lq - 1) {
                if (m_t) c += em[(size_t)id * Tq + tag];
                int tag1 = tags[id + Bn];
                int m1   = mask[id + Bn];
                if (m1) c += trans[tag * Tq + tag1];
                is_last = (m_t != 0) && (m1 == 0);
            } else {
                is_last = (m_t != 0);
            }
            if (is_last) {
                c += endT[tag];
                int mL = mask[(Lq - 1) * Bn + bb];
                if (mL) c += em[((size_t)(Lq - 1) * Bn + bb) * Tq + tag];
            }
        }
#pragma unroll
        for (int off = 32; off >= 1; off >>= 1)
            c += __shfl_xor(c, off, 64);
        if (j == 0) atomicAdd(out, c);
    }
}

extern "C" void kernel_launch(void* const* d_in, const int* in_sizes, int n_in,
                              void* d_out, int out_size, void* d_ws, size_t ws_size,
                              hipStream_t stream) {
    const float* em     = (const float*)d_in[0];
    const int*   tags   = (const int*)d_in[1];
    const int*   mask   = (const int*)d_in[2];
    const float* startT = (const float*)d_in[3];
    const float* endT   = (const float*)d_in[4];
    const float* trans  = (const float*)d_in[5];
    float* out = (float*)d_out;

    hipMemsetAsync(out, 0, sizeof(float), stream);
    crf_fused<<<576, 64, 0, stream>>>(em, tags, mask, startT, endT, trans, out);
}